// Round 15
// baseline (177.286 us; speedup 1.0000x reference)
//
#include <hip/hip_runtime.h>
#include <math.h>

// AAttn bf16-MFMA pipeline v9. B=8, C=256, H=W=64, N=4096, AREA=4.
// ws: qt   bf16 [8][4096][512]  (q ch0..255 scaled by d^-.5*log2e, k ch256..511)
//     vbuf bf16 [8][256][4096]
//     opp  bf16 [8][256][4096]  (pp then += attention out)   <-- now bf16
//     wqkh/wvh/wprojh bf16 weights in MFMA-FRAGMENT order
// v9 = v8 attn (verified) with bf16 opp epilogue; qkv on 32-pos strips
//      (1024 blocks, 4/CU); pe/proj on bf16 opp.

#define NN 4096
#define NA 1024

typedef unsigned short us;
typedef __attribute__((ext_vector_type(4))) unsigned short us4;
typedef __attribute__((ext_vector_type(8))) unsigned short us8;
typedef __attribute__((ext_vector_type(8))) short bf16x8;
typedef __attribute__((ext_vector_type(4))) float f32x4;

#define QS (0.17677669529663687f * 1.4426950408889634f)   // d^-0.5 * log2(e)

__device__ __forceinline__ us f2b(float f) {
    unsigned u = __builtin_bit_cast(unsigned, f);
    u += 0x7fffu + ((u >> 16) & 1u);              // RNE
    return (us)(u >> 16);
}
__device__ __forceinline__ float b2f(us h) {
    unsigned u = ((unsigned)h) << 16;
    return __builtin_bit_cast(float, u);
}
__device__ __forceinline__ unsigned pack2(float lo, float hi) {
    return (unsigned)f2b(lo) | ((unsigned)f2b(hi) << 16);
}
__device__ __forceinline__ unsigned cvtpk_bf16(float lo, float hi) {
    unsigned r;
    asm("v_cvt_pk_bf16_f32 %0, %1, %2" : "=v"(r) : "v"(lo), "v"(hi));
    return r;
}
// raw 2^x: inputs bounded here so libm's denormal fixup is dead weight
__device__ __forceinline__ float fexp2(float x) {
    float r;
    asm("v_exp_f32 %0, %1" : "=v"(r) : "v"(x));
    return r;
}

// fragment-order index: (ch,k) -> ((ch>>4)*8 + (k>>5))*512 + (((k>>3)&3)*16 + (ch&15))*8 + (k&7)
__device__ __forceinline__ size_t wswz(int ch, int k) {
    return ((size_t)((ch >> 4) * 8 + (k >> 5))) * 512 + ((((k >> 3) & 3) * 16 + (ch & 15))) * 8 + (k & 7);
}

// ---------------- weight prep: fold BN scale, bf16, fragment order ----------
__global__ __launch_bounds__(256) void prep_kernel(
    const float* __restrict__ w_qk, const float* __restrict__ s_qk, const float* __restrict__ b_qk,
    const float* __restrict__ w_v,  const float* __restrict__ s_v,
    const float* __restrict__ w_proj, const float* __restrict__ s_proj,
    us* __restrict__ wqkh, us* __restrict__ wvh, us* __restrict__ wprojh,
    float* __restrict__ bqkp)
{
    int idx = blockIdx.x * 256 + threadIdx.x;
    if (idx < 131072) {
        int o = idx >> 8, k = idx & 255;
        float sc = s_qk[o] * (o < 256 ? QS : 1.0f);
        wqkh[wswz(o, k)] = f2b(w_qk[idx] * sc);
    } else if (idx < 196608) {
        int j = idx - 131072; int o = j >> 8, k = j & 255;
        wvh[wswz(o, k)] = f2b(w_v[j] * s_v[o]);
    } else {
        int j = idx - 196608; int o = j >> 8, k = j & 255;
        wprojh[wswz(o, k)] = f2b(w_proj[j] * s_proj[o]);
    }
    if (idx < 512) bqkp[idx] = b_qk[idx] * (idx < 256 ? QS : 1.0f);
}

// ---------------- qkv GEMM: 32-pos strips (1024 blocks, 4/CU) ---------------
__global__ __launch_bounds__(256) void qkv_kernel(
    const float* __restrict__ x,
    const us* __restrict__ wqkh, const float* __restrict__ bqkp,
    const us* __restrict__ wvh,  const float* __restrict__ b_v,
    us* __restrict__ qt, us* __restrict__ vbuf)
{
    const int n0 = blockIdx.x * 32;
    const int b  = blockIdx.y;
    const int tid = threadIdx.x;
    const int w = tid >> 6, lane = tid & 63, c = lane & 15, g = lane >> 4;

    __shared__ __align__(16) us Xs[32][264];   // [pos][cin], 528B rows

    const float* Xb = x + (size_t)b * 256 * NN;
    #pragma unroll
    for (int i = 0; i < 8; i++) {
        int t = tid + i * 256;                 // 2048 tasks: 128 cin-pairs x 16 pos-pairs
        int cp = t >> 4, pp = t & 15;
        const float* r0 = Xb + (size_t)(2 * cp) * NN + n0 + 2 * pp;
        float2 a0 = *(const float2*)r0;
        float2 a1 = *(const float2*)(r0 + NN);
        *(unsigned*)&Xs[2 * pp][2 * cp]     = pack2(a0.x, a1.x);
        *(unsigned*)&Xs[2 * pp + 1][2 * cp] = pack2(a0.y, a1.y);
    }
    __syncthreads();

    for (int grp = 0; grp < 3; grp++) {
        f32x4 acc[4][2] = {};                  // [cgi][j]
        for (int kc = 0; kc < 256; kc += 32) {
            bf16x8 Xf[2];
            #pragma unroll
            for (int j = 0; j < 2; j++)
                Xf[j] = *(const bf16x8*)&Xs[j * 16 + c][kc + g * 8];
            #pragma unroll
            for (int cgi = 0; cgi < 4; cgi++) {
                int chbase = (grp < 2 ? (grp * 4 + cgi) * 64 : cgi * 64);
                const us* Wp = (grp < 2 ? wqkh : wvh) +
                    ((size_t)(((chbase >> 4) + w) * 8 + (kc >> 5))) * 512 + lane * 8;
                bf16x8 Wf = *(const bf16x8*)Wp;   // coalesced 1KB wave load
                if (grp < 2) {   // A=X(pos), B=W(ch) -> D[pos][ch]
                    #pragma unroll
                    for (int j = 0; j < 2; j++)
                        acc[cgi][j] = __builtin_amdgcn_mfma_f32_16x16x32_bf16(Xf[j], Wf, acc[cgi][j], 0, 0, 0);
                } else {         // A=W(ch), B=X(pos) -> D[ch][pos]
                    #pragma unroll
                    for (int j = 0; j < 2; j++)
                        acc[cgi][j] = __builtin_amdgcn_mfma_f32_16x16x32_bf16(Wf, Xf[j], acc[cgi][j], 0, 0, 0);
                }
            }
        }
        if (grp < 2) {
            #pragma unroll
            for (int cgi = 0; cgi < 4; cgi++) {
                int ch = (grp * 4 + cgi) * 64 + w * 16 + c;
                float bb = bqkp[ch];
                #pragma unroll
                for (int j = 0; j < 2; j++)
                    #pragma unroll
                    for (int r = 0; r < 4; r++)
                        qt[((size_t)b * 4096 + n0 + j * 16 + g * 4 + r) * 512 + ch] =
                            f2b(acc[cgi][j][r] + bb);
            }
        } else {
            #pragma unroll
            for (int cgi = 0; cgi < 4; cgi++)
                #pragma unroll
                for (int r = 0; r < 4; r++) {
                    int ch = cgi * 64 + w * 16 + g * 4 + r;
                    float bb = b_v[ch];
                    #pragma unroll
                    for (int j = 0; j < 2; j++)
                        vbuf[((size_t)b * 256 + ch) * NN + n0 + j * 16 + c] =
                            f2b(acc[cgi][j][r] + bb);
                }
        }
    }
}

// ---------------- depthwise 5x5 'SAME' on v(bf16), writes pp(bf16) ----------
__global__ __launch_bounds__(256) void pe_conv_kernel(
    const us* __restrict__ vbuf,
    const float* __restrict__ w_pe, const float* __restrict__ s_pe, const float* __restrict__ b_pe,
    us* __restrict__ opp)
{
    const int c = blockIdx.x, b = blockIdx.y;
    const int tid = threadIdx.x;
    const us* vp = vbuf + ((size_t)b * 256 + c) * NN;
    __shared__ float plane[4096];
    __shared__ float wloc[25];
    #pragma unroll
    for (int i = 0; i < 4; i++) {
        int idx = tid + i * 256;
        us4 v = *(const us4*)&vp[idx * 4];
        float4 f;
        f.x = b2f(v[0]); f.y = b2f(v[1]); f.z = b2f(v[2]); f.w = b2f(v[3]);
        *(float4*)&plane[idx * 4] = f;
    }
    if (tid < 25) wloc[tid] = w_pe[c * 25 + tid];
    __syncthreads();

    const float s = s_pe[c], bb = b_pe[c];
    us* op = opp + ((size_t)b * 256 + c) * NN;
    for (int i = 0; i < 16; i++) {
        int pix = tid + i * 256;
        int ph = pix >> 6, pw = pix & 63;
        float acc = 0.f;
        #pragma unroll
        for (int dy = -2; dy <= 2; dy++) {
            int hy = ph + dy;
            if (hy < 0 || hy > 63) continue;
            #pragma unroll
            for (int dx = -2; dx <= 2; dx++) {
                int wx = pw + dx;
                if (wx < 0 || wx > 63) continue;
                acc += plane[hy * 64 + wx] * wloc[(dy + 2) * 5 + (dx + 2)];
            }
        }
        op[pix] = f2b(acc * s + bb);
    }
}

// ---------------- flash attention v8 core, bf16 opp epilogue ----------------
__global__ __launch_bounds__(256) void attn_kernel(
    const us* __restrict__ qt, const us* __restrict__ vbuf, us* __restrict__ opp)
{
    const int h   = blockIdx.x;   // 8  (x so same-(h,ba) blocks share XCD L2)
    const int qtb = blockIdx.y;   // 8 q-tiles of 128
    const int ba  = blockIdx.z;   // 32
    const int b = ba >> 2, a = ba & 3;
    const int tid = threadIdx.x;
    const int w = tid >> 6, lane = tid & 63, c = lane & 15, g = lane >> 4;
    const int q0 = qtb * 128;

    __shared__ __align__(16) us Kt[2][64][40];    // [key][d] dbuf
    __shared__ __align__(16) us Vs[2][2048];      // 32 rows x 128B, XOR-swizzled 16B slots
    __shared__ __align__(16) us Ps[128][72];      // wave-private rows

    // staging roles (one 16B load+write per buffer per thread)
    const int krow = tid >> 2, kseg = tid & 3;    // 64 rows x 32 d
    const int vrow = tid >> 3, vseg = tid & 7;    // 32 rows x 64 keys
    const int vbyte = vrow * 128 + ((vseg ^ (vrow & 7)) << 4);

    const us* Kg = qt + ((size_t)b * 4096 + a * NA) * 512 + 256 + h * 32;
    const us* Vg = vbuf + ((size_t)b * 256 + h * 32) * NN + a * NA;

    // Q fragments direct to registers
    const us* Qp = qt + ((size_t)b * 4096 + a * NA + q0 + w * 16 + c) * 512 + h * 32 + g * 8;
    const bf16x8 Qf0 = *(const bf16x8*)Qp;
    const bf16x8 Qf1 = *(const bf16x8*)(Qp + (size_t)64 * 512);

    // prologue: stage tile 0
    {
        us8 kreg = *(const us8*)(Kg + (size_t)krow * 512 + kseg * 8);
        us8 vreg = *(const us8*)(Vg + (size_t)vrow * NN + vseg * 8);
        *(us8*)&Kt[0][krow][kseg * 8] = kreg;
        *(us8*)((char*)Vs[0] + vbyte) = vreg;
    }
    __syncthreads();

    const bf16x8 ones = {0x3F80, 0x3F80, 0x3F80, 0x3F80, 0x3F80, 0x3F80, 0x3F80, 0x3F80};
    const f32x4 z = {0.f, 0.f, 0.f, 0.f};
    const int qr0 = w * 16 + c, qr1 = 64 + w * 16 + c;

    f32x4 O0a = z, O1a = z, Osa = z;
    f32x4 O0b = z, O1b = z, Osb = z;
    int cur = 0;

    for (int kt = 0; kt < 16; kt++) {
        // issue next tile's global loads early (latency hides under compute)
        us8 kreg, vreg;
        if (kt < 15) {
            const int kv1 = (kt + 1) * 64;
            kreg = *(const us8*)(Kg + ((size_t)(kv1 + krow)) * 512 + kseg * 8);
            vreg = *(const us8*)(Vg + (size_t)vrow * NN + kv1 + vseg * 8);
        }

        // S^T: A=K rows, B=Q halves -> S[key=j*16+g*4+r][q]
        f32x4 sA[4], sB[4];
        #pragma unroll
        for (int j = 0; j < 4; j++) {
            bf16x8 Kf = *(const bf16x8*)&Kt[cur][j * 16 + c][g * 8];
            sA[j] = __builtin_amdgcn_mfma_f32_16x16x32_bf16(Kf, Qf0, z, 0, 0, 0);
            sB[j] = __builtin_amdgcn_mfma_f32_16x16x32_bf16(Kf, Qf1, z, 0, 0, 0);
        }

        // half a: exp2 + pack -> Ps rows 0..63
        #pragma unroll
        for (int j = 0; j < 4; j++) {
            uint2 pr;
            pr.x = cvtpk_bf16(fexp2(sA[j][0]), fexp2(sA[j][1]));
            pr.y = cvtpk_bf16(fexp2(sA[j][2]), fexp2(sA[j][3]));
            *(uint2*)&Ps[qr0][j * 16 + g * 4] = pr;
        }
        asm volatile("s_waitcnt lgkmcnt(0)" ::: "memory");
        __builtin_amdgcn_sched_barrier(0);

        // half b exp2/pack (trans+VALU) overlaps PV-a MFMAs below
        uint2 prb[4];
        #pragma unroll
        for (int j = 0; j < 4; j++) {
            prb[j].x = cvtpk_bf16(fexp2(sB[j][0]), fexp2(sB[j][1]));
            prb[j].y = cvtpk_bf16(fexp2(sB[j][2]), fexp2(sB[j][3]));
        }

        // PV-a: O += P V ; l += P * 1
        #pragma unroll
        for (int ks = 0; ks < 2; ks++) {
            int so = (((ks * 4 + g) ^ (c & 7)) << 4);
            bf16x8 Bv0 = *(const bf16x8*)((char*)Vs[cur] + c * 128 + so);
            bf16x8 Bv1 = *(const bf16x8*)((char*)Vs[cur] + (16 + c) * 128 + so);
            bf16x8 Ap0 = *(const bf16x8*)&Ps[qr0][ks * 32 + g * 8];
            O0a = __builtin_amdgcn_mfma_f32_16x16x32_bf16(Ap0, Bv0, O0a, 0, 0, 0);
            O1a = __builtin_amdgcn_mfma_f32_16x16x32_bf16(Ap0, Bv1, O1a, 0, 0, 0);
            Osa = __builtin_amdgcn_mfma_f32_16x16x32_bf16(Ap0, ones, Osa, 0, 0, 0);
        }

        // half b: write packs -> Ps rows 64..127
        #pragma unroll
        for (int j = 0; j < 4; j++)
            *(uint2*)&Ps[qr1][j * 16 + g * 4] = prb[j];
        asm volatile("s_waitcnt lgkmcnt(0)" ::: "memory");
        __builtin_amdgcn_sched_barrier(0);

        // PV-b
        #pragma unroll
        for (int ks = 0; ks < 2; ks++) {
            int so = (((ks * 4 + g) ^ (c & 7)) << 4);
            bf16x8 Bv0 = *(const bf16x8*)((char*)Vs[cur] + c * 128 + so);
            bf16x8 Bv1 = *(const bf16x8*)((char*)Vs[cur] + (16 + c) * 128 + so);
            bf16x8 Ap1 = *(const bf16x8*)&Ps[qr1][ks * 32 + g * 8];
            O0b = __builtin_amdgcn_mfma_f32_16x16x32_bf16(Ap1, Bv0, O0b, 0, 0, 0);
            O1b = __builtin_amdgcn_mfma_f32_16x16x32_bf16(Ap1, Bv1, O1b, 0, 0, 0);
            Osb = __builtin_amdgcn_mfma_f32_16x16x32_bf16(Ap1, ones, Osb, 0, 0, 0);
        }

        // write next buffer (compiler inserts vmcnt wait for kreg/vreg)
        if (kt < 15) {
            *(us8*)&Kt[cur ^ 1][krow][kseg * 8] = kreg;
            *(us8*)((char*)Vs[cur ^ 1] + vbyte) = vreg;
        }
        __syncthreads();
        cur ^= 1;
    }

    // Osum[r] = l for q-row (PV layout); RMW bf16 opp, both q-halves
    float linva[4], linvb[4];
    #pragma unroll
    for (int r = 0; r < 4; r++) { linva[r] = 1.0f / Osa[r]; linvb[r] = 1.0f / Osb[r]; }

    us* Ob = opp + ((size_t)(b * 256 + h * 32)) * NN + a * NA + q0 + w * 16 + g * 4;
    {
        us4 o = *(us4*)(Ob + (size_t)c * NN);
        #pragma unroll
        for (int r = 0; r < 4; r++) o[r] = f2b(b2f(o[r]) + O0a[r] * linva[r]);
        *(us4*)(Ob + (size_t)c * NN) = o;
        us4 o2 = *(us4*)(Ob + (size_t)(16 + c) * NN);
        #pragma unroll
        for (int r = 0; r < 4; r++) o2[r] = f2b(b2f(o2[r]) + O1a[r] * linva[r]);
        *(us4*)(Ob + (size_t)(16 + c) * NN) = o2;

        us* Ob2 = Ob + 64;
        us4 o3 = *(us4*)(Ob2 + (size_t)c * NN);
        #pragma unroll
        for (int r = 0; r < 4; r++) o3[r] = f2b(b2f(o3[r]) + O0b[r] * linvb[r]);
        *(us4*)(Ob2 + (size_t)c * NN) = o3;
        us4 o4 = *(us4*)(Ob2 + (size_t)(16 + c) * NN);
        #pragma unroll
        for (int r = 0; r < 4; r++) o4[r] = f2b(b2f(o4[r]) + O1b[r] * linvb[r]);
        *(us4*)(Ob2 + (size_t)(16 + c) * NN) = o4;
    }
}

// ---------------- proj GEMM: bf16 opp staged once, 4 ch-groups --------------
__global__ __launch_bounds__(256) void proj_kernel(
    const us* __restrict__ opp,
    const us* __restrict__ wprojh, const float* __restrict__ b_proj,
    float* __restrict__ out)
{
    const int n0 = blockIdx.x * 64;
    const int b  = blockIdx.y;
    const int tid = threadIdx.x;
    const int w = tid >> 6, lane = tid & 63, c = lane & 15, g = lane >> 4;

    __shared__ __align__(16) us Xs[64][264];

    const us* Xb = opp + (size_t)b * 256 * NN;
    #pragma unroll
    for (int i = 0; i < 16; i++) {
        int t = tid + i * 256;
        int cp = t >> 5, pp = t & 31;
        unsigned a0 = *(const unsigned*)&Xb[(size_t)(2 * cp) * NN + n0 + 2 * pp];
        unsigned a1 = *(const unsigned*)&Xb[(size_t)(2 * cp + 1) * NN + n0 + 2 * pp];
        *(unsigned*)&Xs[2 * pp][2 * cp]     = (a0 & 0xFFFFu) | (a1 << 16);
        *(unsigned*)&Xs[2 * pp + 1][2 * cp] = (a0 >> 16) | (a1 & 0xFFFF0000u);
    }
    __syncthreads();

    f32x4 acc[4][4] = {};                      // [cgi][j]
    for (int kc = 0; kc < 256; kc += 32) {
        bf16x8 Xf[4];
        #pragma unroll
        for (int j = 0; j < 4; j++)
            Xf[j] = *(const bf16x8*)&Xs[j * 16 + c][kc + g * 8];
        #pragma unroll
        for (int cgi = 0; cgi < 4; cgi++) {
            const us* Wp = wprojh +
                ((size_t)((cgi * 4 + w) * 8 + (kc >> 5))) * 512 + lane * 8;
            bf16x8 Wf = *(const bf16x8*)Wp;    // coalesced 1KB wave load
            #pragma unroll
            for (int j = 0; j < 4; j++)    // A=W(ch), B=X(pos) -> D[ch][pos]
                acc[cgi][j] = __builtin_amdgcn_mfma_f32_16x16x32_bf16(Wf, Xf[j], acc[cgi][j], 0, 0, 0);
        }
    }

    #pragma unroll
    for (int cgi = 0; cgi < 4; cgi++)
        #pragma unroll
        for (int r = 0; r < 4; r++) {
            int ch = cgi * 64 + w * 16 + g * 4 + r;
            float bb = b_proj[ch];
            #pragma unroll
            for (int j = 0; j < 4; j++)
                out[((size_t)b * 256 + ch) * NN + n0 + j * 16 + c] = acc[cgi][j][r] + bb;
        }
}

extern "C" void kernel_launch(void* const* d_in, const int* in_sizes, int n_in,
                              void* d_out, int out_size, void* d_ws, size_t ws_size,
                              hipStream_t stream) {
    const float* x      = (const float*)d_in[0];
    const float* w_qk   = (const float*)d_in[1];
    const float* s_qk   = (const float*)d_in[2];
    const float* b_qk   = (const float*)d_in[3];
    const float* w_v    = (const float*)d_in[4];
    const float* s_v    = (const float*)d_in[5];
    const float* b_v    = (const float*)d_in[6];
    const float* w_pe   = (const float*)d_in[7];
    const float* s_pe   = (const float*)d_in[8];
    const float* b_pe   = (const float*)d_in[9];
    const float* w_proj = (const float*)d_in[10];
    const float* s_proj = (const float*)d_in[11];
    const float* b_proj = (const float*)d_in[12];
    float* out = (float*)d_out;

    char* p = (char*)d_ws;
    us* qtb     = (us*)p;                  p += (size_t)8 * 4096 * 512 * 2;   // 32M
    us* vbuf    = (us*)p;                  p += (size_t)8 * 256 * 4096 * 2;   // 16M
    us* opp     = (us*)p;                  p += (size_t)8 * 256 * 4096 * 2;   // 16M
    us* wqkh    = (us*)p;                  p += (size_t)512 * 256 * 2;
    us* wvh     = (us*)p;                  p += (size_t)256 * 256 * 2;
    us* wprojh  = (us*)p;                  p += (size_t)256 * 256 * 2;
    float* bqkp = (float*)p;

    prep_kernel<<<1024, 256, 0, stream>>>(w_qk, s_qk, b_qk, w_v, s_v,
                                          w_proj, s_proj, wqkh, wvh, wprojh, bqkp);
    qkv_kernel<<<dim3(128, 8), 256, 0, stream>>>(x, wqkh, bqkp, wvh, b_v, qtb, vbuf);
    pe_conv_kernel<<<dim3(256, 8), 256, 0, stream>>>(vbuf, w_pe, s_pe, b_pe, opp);
    attn_kernel<<<dim3(8, 8, 32), 256, 0, stream>>>(qtb, vbuf, opp);
    proj_kernel<<<dim3(64, 8), 256, 0, stream>>>(opp, wprojh, b_proj, out);
}

// Round 16
// 152.506 us; speedup vs baseline: 1.1625x; 1.1625x over previous
//
#include <hip/hip_runtime.h>
#include <math.h>

// AAttn bf16-MFMA pipeline v10. B=8, C=256, H=W=64, N=4096, AREA=4.
// ws: qt   bf16 [8][4096][512]  (q ch0..255 scaled by d^-.5*log2e, k ch256..511)
//     vbuf bf16 [8][256][4096]
//     opp  bf16 [8][256][4096]  (pp then += attention out)
//     wqkh/wvh/wprojh bf16 weights in MFMA-FRAGMENT order
// v10 = v9 with qkv reverted to the verified 64-pos-strip version
//       (32-strip experiment was latency-bound: 2 MFMA per W load too few).

#define NN 4096
#define NA 1024

typedef unsigned short us;
typedef __attribute__((ext_vector_type(4))) unsigned short us4;
typedef __attribute__((ext_vector_type(8))) unsigned short us8;
typedef __attribute__((ext_vector_type(8))) short bf16x8;
typedef __attribute__((ext_vector_type(4))) float f32x4;

#define QS (0.17677669529663687f * 1.4426950408889634f)   // d^-0.5 * log2(e)

__device__ __forceinline__ us f2b(float f) {
    unsigned u = __builtin_bit_cast(unsigned, f);
    u += 0x7fffu + ((u >> 16) & 1u);              // RNE
    return (us)(u >> 16);
}
__device__ __forceinline__ float b2f(us h) {
    unsigned u = ((unsigned)h) << 16;
    return __builtin_bit_cast(float, u);
}
__device__ __forceinline__ unsigned pack2(float lo, float hi) {
    return (unsigned)f2b(lo) | ((unsigned)f2b(hi) << 16);
}
__device__ __forceinline__ unsigned cvtpk_bf16(float lo, float hi) {
    unsigned r;
    asm("v_cvt_pk_bf16_f32 %0, %1, %2" : "=v"(r) : "v"(lo), "v"(hi));
    return r;
}
// raw 2^x: inputs bounded here so libm's denormal fixup is dead weight
__device__ __forceinline__ float fexp2(float x) {
    float r;
    asm("v_exp_f32 %0, %1" : "=v"(r) : "v"(x));
    return r;
}

// fragment-order index: (ch,k) -> ((ch>>4)*8 + (k>>5))*512 + (((k>>3)&3)*16 + (ch&15))*8 + (k&7)
__device__ __forceinline__ size_t wswz(int ch, int k) {
    return ((size_t)((ch >> 4) * 8 + (k >> 5))) * 512 + ((((k >> 3) & 3) * 16 + (ch & 15))) * 8 + (k & 7);
}

// ---------------- weight prep: fold BN scale, bf16, fragment order ----------
__global__ __launch_bounds__(256) void prep_kernel(
    const float* __restrict__ w_qk, const float* __restrict__ s_qk, const float* __restrict__ b_qk,
    const float* __restrict__ w_v,  const float* __restrict__ s_v,
    const float* __restrict__ w_proj, const float* __restrict__ s_proj,
    us* __restrict__ wqkh, us* __restrict__ wvh, us* __restrict__ wprojh,
    float* __restrict__ bqkp)
{
    int idx = blockIdx.x * 256 + threadIdx.x;
    if (idx < 131072) {
        int o = idx >> 8, k = idx & 255;
        float sc = s_qk[o] * (o < 256 ? QS : 1.0f);
        wqkh[wswz(o, k)] = f2b(w_qk[idx] * sc);
    } else if (idx < 196608) {
        int j = idx - 131072; int o = j >> 8, k = j & 255;
        wvh[wswz(o, k)] = f2b(w_v[j] * s_v[o]);
    } else {
        int j = idx - 196608; int o = j >> 8, k = j & 255;
        wprojh[wswz(o, k)] = f2b(w_proj[j] * s_proj[o]);
    }
    if (idx < 512) bqkp[idx] = b_qk[idx] * (idx < 256 ? QS : 1.0f);
}

// ---------------- qkv GEMM: x f32 staged once (64-pos strips), 12 ch-groups -
__global__ __launch_bounds__(256) void qkv_kernel(
    const float* __restrict__ x,
    const us* __restrict__ wqkh, const float* __restrict__ bqkp,
    const us* __restrict__ wvh,  const float* __restrict__ b_v,
    us* __restrict__ qt, us* __restrict__ vbuf)
{
    const int n0 = blockIdx.x * 64;
    const int b  = blockIdx.y;
    const int tid = threadIdx.x;
    const int w = tid >> 6, lane = tid & 63, c = lane & 15, g = lane >> 4;

    __shared__ __align__(16) us Xs[64][264];   // [pos][cin], 528B rows

    const float* Xb = x + (size_t)b * 256 * NN;
    #pragma unroll
    for (int i = 0; i < 16; i++) {
        int t = tid + i * 256;                 // 4096 tasks: 128 cin-pairs x 32 pos-pairs
        int cp = t >> 5, pp = t & 31;
        const float* r0 = Xb + (size_t)(2 * cp) * NN + n0 + 2 * pp;
        float2 a0 = *(const float2*)r0;
        float2 a1 = *(const float2*)(r0 + NN);
        *(unsigned*)&Xs[2 * pp][2 * cp]     = pack2(a0.x, a1.x);
        *(unsigned*)&Xs[2 * pp + 1][2 * cp] = pack2(a0.y, a1.y);
    }
    __syncthreads();

    for (int grp = 0; grp < 3; grp++) {
        f32x4 acc[4][4] = {};                  // [cgi][j]
        for (int kc = 0; kc < 256; kc += 32) {
            bf16x8 Xf[4];
            #pragma unroll
            for (int j = 0; j < 4; j++)
                Xf[j] = *(const bf16x8*)&Xs[j * 16 + c][kc + g * 8];
            #pragma unroll
            for (int cgi = 0; cgi < 4; cgi++) {
                int chbase = (grp < 2 ? (grp * 4 + cgi) * 64 : cgi * 64);
                const us* Wp = (grp < 2 ? wqkh : wvh) +
                    ((size_t)(((chbase >> 4) + w) * 8 + (kc >> 5))) * 512 + lane * 8;
                bf16x8 Wf = *(const bf16x8*)Wp;   // coalesced 1KB wave load
                if (grp < 2) {   // A=X(pos), B=W(ch) -> D[pos][ch]
                    #pragma unroll
                    for (int j = 0; j < 4; j++)
                        acc[cgi][j] = __builtin_amdgcn_mfma_f32_16x16x32_bf16(Xf[j], Wf, acc[cgi][j], 0, 0, 0);
                } else {         // A=W(ch), B=X(pos) -> D[ch][pos]
                    #pragma unroll
                    for (int j = 0; j < 4; j++)
                        acc[cgi][j] = __builtin_amdgcn_mfma_f32_16x16x32_bf16(Wf, Xf[j], acc[cgi][j], 0, 0, 0);
                }
            }
        }
        if (grp < 2) {
            #pragma unroll
            for (int cgi = 0; cgi < 4; cgi++) {
                int ch = (grp * 4 + cgi) * 64 + w * 16 + c;
                float bb = bqkp[ch];
                #pragma unroll
                for (int j = 0; j < 4; j++)
                    #pragma unroll
                    for (int r = 0; r < 4; r++)
                        qt[((size_t)b * 4096 + n0 + j * 16 + g * 4 + r) * 512 + ch] =
                            f2b(acc[cgi][j][r] + bb);
            }
        } else {
            #pragma unroll
            for (int cgi = 0; cgi < 4; cgi++)
                #pragma unroll
                for (int r = 0; r < 4; r++) {
                    int ch = cgi * 64 + w * 16 + g * 4 + r;
                    float bb = b_v[ch];
                    #pragma unroll
                    for (int j = 0; j < 4; j++)
                        vbuf[((size_t)b * 256 + ch) * NN + n0 + j * 16 + c] =
                            f2b(acc[cgi][j][r] + bb);
                }
        }
    }
}

// ---------------- depthwise 5x5 'SAME' on v(bf16), writes pp(bf16) ----------
__global__ __launch_bounds__(256) void pe_conv_kernel(
    const us* __restrict__ vbuf,
    const float* __restrict__ w_pe, const float* __restrict__ s_pe, const float* __restrict__ b_pe,
    us* __restrict__ opp)
{
    const int c = blockIdx.x, b = blockIdx.y;
    const int tid = threadIdx.x;
    const us* vp = vbuf + ((size_t)b * 256 + c) * NN;
    __shared__ float plane[4096];
    __shared__ float wloc[25];
    #pragma unroll
    for (int i = 0; i < 4; i++) {
        int idx = tid + i * 256;
        us4 v = *(const us4*)&vp[idx * 4];
        float4 f;
        f.x = b2f(v[0]); f.y = b2f(v[1]); f.z = b2f(v[2]); f.w = b2f(v[3]);
        *(float4*)&plane[idx * 4] = f;
    }
    if (tid < 25) wloc[tid] = w_pe[c * 25 + tid];
    __syncthreads();

    const float s = s_pe[c], bb = b_pe[c];
    us* op = opp + ((size_t)b * 256 + c) * NN;
    for (int i = 0; i < 16; i++) {
        int pix = tid + i * 256;
        int ph = pix >> 6, pw = pix & 63;
        float acc = 0.f;
        #pragma unroll
        for (int dy = -2; dy <= 2; dy++) {
            int hy = ph + dy;
            if (hy < 0 || hy > 63) continue;
            #pragma unroll
            for (int dx = -2; dx <= 2; dx++) {
                int wx = pw + dx;
                if (wx < 0 || wx > 63) continue;
                acc += plane[hy * 64 + wx] * wloc[(dy + 2) * 5 + (dx + 2)];
            }
        }
        op[pix] = f2b(acc * s + bb);
    }
}

// ---------------- flash attention v8 core, bf16 opp epilogue ----------------
__global__ __launch_bounds__(256) void attn_kernel(
    const us* __restrict__ qt, const us* __restrict__ vbuf, us* __restrict__ opp)
{
    const int h   = blockIdx.x;   // 8  (x so same-(h,ba) blocks share XCD L2)
    const int qtb = blockIdx.y;   // 8 q-tiles of 128
    const int ba  = blockIdx.z;   // 32
    const int b = ba >> 2, a = ba & 3;
    const int tid = threadIdx.x;
    const int w = tid >> 6, lane = tid & 63, c = lane & 15, g = lane >> 4;
    const int q0 = qtb * 128;

    __shared__ __align__(16) us Kt[2][64][40];    // [key][d] dbuf
    __shared__ __align__(16) us Vs[2][2048];      // 32 rows x 128B, XOR-swizzled 16B slots
    __shared__ __align__(16) us Ps[128][72];      // wave-private rows

    // staging roles (one 16B load+write per buffer per thread)
    const int krow = tid >> 2, kseg = tid & 3;    // 64 rows x 32 d
    const int vrow = tid >> 3, vseg = tid & 7;    // 32 rows x 64 keys
    const int vbyte = vrow * 128 + ((vseg ^ (vrow & 7)) << 4);

    const us* Kg = qt + ((size_t)b * 4096 + a * NA) * 512 + 256 + h * 32;
    const us* Vg = vbuf + ((size_t)b * 256 + h * 32) * NN + a * NA;

    // Q fragments direct to registers
    const us* Qp = qt + ((size_t)b * 4096 + a * NA + q0 + w * 16 + c) * 512 + h * 32 + g * 8;
    const bf16x8 Qf0 = *(const bf16x8*)Qp;
    const bf16x8 Qf1 = *(const bf16x8*)(Qp + (size_t)64 * 512);

    // prologue: stage tile 0
    {
        us8 kreg = *(const us8*)(Kg + (size_t)krow * 512 + kseg * 8);
        us8 vreg = *(const us8*)(Vg + (size_t)vrow * NN + vseg * 8);
        *(us8*)&Kt[0][krow][kseg * 8] = kreg;
        *(us8*)((char*)Vs[0] + vbyte) = vreg;
    }
    __syncthreads();

    const bf16x8 ones = {0x3F80, 0x3F80, 0x3F80, 0x3F80, 0x3F80, 0x3F80, 0x3F80, 0x3F80};
    const f32x4 z = {0.f, 0.f, 0.f, 0.f};
    const int qr0 = w * 16 + c, qr1 = 64 + w * 16 + c;

    f32x4 O0a = z, O1a = z, Osa = z;
    f32x4 O0b = z, O1b = z, Osb = z;
    int cur = 0;

    for (int kt = 0; kt < 16; kt++) {
        // issue next tile's global loads early (latency hides under compute)
        us8 kreg, vreg;
        if (kt < 15) {
            const int kv1 = (kt + 1) * 64;
            kreg = *(const us8*)(Kg + ((size_t)(kv1 + krow)) * 512 + kseg * 8);
            vreg = *(const us8*)(Vg + (size_t)vrow * NN + kv1 + vseg * 8);
        }

        // S^T: A=K rows, B=Q halves -> S[key=j*16+g*4+r][q]
        f32x4 sA[4], sB[4];
        #pragma unroll
        for (int j = 0; j < 4; j++) {
            bf16x8 Kf = *(const bf16x8*)&Kt[cur][j * 16 + c][g * 8];
            sA[j] = __builtin_amdgcn_mfma_f32_16x16x32_bf16(Kf, Qf0, z, 0, 0, 0);
            sB[j] = __builtin_amdgcn_mfma_f32_16x16x32_bf16(Kf, Qf1, z, 0, 0, 0);
        }

        // half a: exp2 + pack -> Ps rows 0..63
        #pragma unroll
        for (int j = 0; j < 4; j++) {
            uint2 pr;
            pr.x = cvtpk_bf16(fexp2(sA[j][0]), fexp2(sA[j][1]));
            pr.y = cvtpk_bf16(fexp2(sA[j][2]), fexp2(sA[j][3]));
            *(uint2*)&Ps[qr0][j * 16 + g * 4] = pr;
        }
        asm volatile("s_waitcnt lgkmcnt(0)" ::: "memory");
        __builtin_amdgcn_sched_barrier(0);

        // half b exp2/pack (trans+VALU) overlaps PV-a MFMAs below
        uint2 prb[4];
        #pragma unroll
        for (int j = 0; j < 4; j++) {
            prb[j].x = cvtpk_bf16(fexp2(sB[j][0]), fexp2(sB[j][1]));
            prb[j].y = cvtpk_bf16(fexp2(sB[j][2]), fexp2(sB[j][3]));
        }

        // PV-a: O += P V ; l += P * 1
        #pragma unroll
        for (int ks = 0; ks < 2; ks++) {
            int so = (((ks * 4 + g) ^ (c & 7)) << 4);
            bf16x8 Bv0 = *(const bf16x8*)((char*)Vs[cur] + c * 128 + so);
            bf16x8 Bv1 = *(const bf16x8*)((char*)Vs[cur] + (16 + c) * 128 + so);
            bf16x8 Ap0 = *(const bf16x8*)&Ps[qr0][ks * 32 + g * 8];
            O0a = __builtin_amdgcn_mfma_f32_16x16x32_bf16(Ap0, Bv0, O0a, 0, 0, 0);
            O1a = __builtin_amdgcn_mfma_f32_16x16x32_bf16(Ap0, Bv1, O1a, 0, 0, 0);
            Osa = __builtin_amdgcn_mfma_f32_16x16x32_bf16(Ap0, ones, Osa, 0, 0, 0);
        }

        // half b: write packs -> Ps rows 64..127
        #pragma unroll
        for (int j = 0; j < 4; j++)
            *(uint2*)&Ps[qr1][j * 16 + g * 4] = prb[j];
        asm volatile("s_waitcnt lgkmcnt(0)" ::: "memory");
        __builtin_amdgcn_sched_barrier(0);

        // PV-b
        #pragma unroll
        for (int ks = 0; ks < 2; ks++) {
            int so = (((ks * 4 + g) ^ (c & 7)) << 4);
            bf16x8 Bv0 = *(const bf16x8*)((char*)Vs[cur] + c * 128 + so);
            bf16x8 Bv1 = *(const bf16x8*)((char*)Vs[cur] + (16 + c) * 128 + so);
            bf16x8 Ap1 = *(const bf16x8*)&Ps[qr1][ks * 32 + g * 8];
            O0b = __builtin_amdgcn_mfma_f32_16x16x32_bf16(Ap1, Bv0, O0b, 0, 0, 0);
            O1b = __builtin_amdgcn_mfma_f32_16x16x32_bf16(Ap1, Bv1, O1b, 0, 0, 0);
            Osb = __builtin_amdgcn_mfma_f32_16x16x32_bf16(Ap1, ones, Osb, 0, 0, 0);
        }

        // write next buffer (compiler inserts vmcnt wait for kreg/vreg)
        if (kt < 15) {
            *(us8*)&Kt[cur ^ 1][krow][kseg * 8] = kreg;
            *(us8*)((char*)Vs[cur ^ 1] + vbyte) = vreg;
        }
        __syncthreads();
        cur ^= 1;
    }

    // Osum[r] = l for q-row (PV layout); RMW bf16 opp, both q-halves
    float linva[4], linvb[4];
    #pragma unroll
    for (int r = 0; r < 4; r++) { linva[r] = 1.0f / Osa[r]; linvb[r] = 1.0f / Osb[r]; }

    us* Ob = opp + ((size_t)(b * 256 + h * 32)) * NN + a * NA + q0 + w * 16 + g * 4;
    {
        us4 o = *(us4*)(Ob + (size_t)c * NN);
        #pragma unroll
        for (int r = 0; r < 4; r++) o[r] = f2b(b2f(o[r]) + O0a[r] * linva[r]);
        *(us4*)(Ob + (size_t)c * NN) = o;
        us4 o2 = *(us4*)(Ob + (size_t)(16 + c) * NN);
        #pragma unroll
        for (int r = 0; r < 4; r++) o2[r] = f2b(b2f(o2[r]) + O1a[r] * linva[r]);
        *(us4*)(Ob + (size_t)(16 + c) * NN) = o2;

        us* Ob2 = Ob + 64;
        us4 o3 = *(us4*)(Ob2 + (size_t)c * NN);
        #pragma unroll
        for (int r = 0; r < 4; r++) o3[r] = f2b(b2f(o3[r]) + O0b[r] * linvb[r]);
        *(us4*)(Ob2 + (size_t)c * NN) = o3;
        us4 o4 = *(us4*)(Ob2 + (size_t)(16 + c) * NN);
        #pragma unroll
        for (int r = 0; r < 4; r++) o4[r] = f2b(b2f(o4[r]) + O1b[r] * linvb[r]);
        *(us4*)(Ob2 + (size_t)(16 + c) * NN) = o4;
    }
}

// ---------------- proj GEMM: bf16 opp staged once, 4 ch-groups --------------
__global__ __launch_bounds__(256) void proj_kernel(
    const us* __restrict__ opp,
    const us* __restrict__ wprojh, const float* __restrict__ b_proj,
    float* __restrict__ out)
{
    const int n0 = blockIdx.x * 64;
    const int b  = blockIdx.y;
    const int tid = threadIdx.x;
    const int w = tid >> 6, lane = tid & 63, c = lane & 15, g = lane >> 4;

    __shared__ __align__(16) us Xs[64][264];

    const us* Xb = opp + (size_t)b * 256 * NN;
    #pragma unroll
    for (int i = 0; i < 16; i++) {
        int t = tid + i * 256;
        int cp = t >> 5, pp = t & 31;
        unsigned a0 = *(const unsigned*)&Xb[(size_t)(2 * cp) * NN + n0 + 2 * pp];
        unsigned a1 = *(const unsigned*)&Xb[(size_t)(2 * cp + 1) * NN + n0 + 2 * pp];
        *(unsigned*)&Xs[2 * pp][2 * cp]     = (a0 & 0xFFFFu) | (a1 << 16);
        *(unsigned*)&Xs[2 * pp + 1][2 * cp] = (a0 >> 16) | (a1 & 0xFFFF0000u);
    }
    __syncthreads();

    f32x4 acc[4][4] = {};                      // [cgi][j]
    for (int kc = 0; kc < 256; kc += 32) {
        bf16x8 Xf[4];
        #pragma unroll
        for (int j = 0; j < 4; j++)
            Xf[j] = *(const bf16x8*)&Xs[j * 16 + c][kc + g * 8];
        #pragma unroll
        for (int cgi = 0; cgi < 4; cgi++) {
            const us* Wp = wprojh +
                ((size_t)((cgi * 4 + w) * 8 + (kc >> 5))) * 512 + lane * 8;
            bf16x8 Wf = *(const bf16x8*)Wp;    // coalesced 1KB wave load
            #pragma unroll
            for (int j = 0; j < 4; j++)    // A=W(ch), B=X(pos) -> D[ch][pos]
                acc[cgi][j] = __builtin_amdgcn_mfma_f32_16x16x32_bf16(Wf, Xf[j], acc[cgi][j], 0, 0, 0);
        }
    }

    #pragma unroll
    for (int cgi = 0; cgi < 4; cgi++)
        #pragma unroll
        for (int r = 0; r < 4; r++) {
            int ch = cgi * 64 + w * 16 + g * 4 + r;
            float bb = b_proj[ch];
            #pragma unroll
            for (int j = 0; j < 4; j++)
                out[((size_t)b * 256 + ch) * NN + n0 + j * 16 + c] = acc[cgi][j][r] + bb;
        }
}

extern "C" void kernel_launch(void* const* d_in, const int* in_sizes, int n_in,
                              void* d_out, int out_size, void* d_ws, size_t ws_size,
                              hipStream_t stream) {
    const float* x      = (const float*)d_in[0];
    const float* w_qk   = (const float*)d_in[1];
    const float* s_qk   = (const float*)d_in[2];
    const float* b_qk   = (const float*)d_in[3];
    const float* w_v    = (const float*)d_in[4];
    const float* s_v    = (const float*)d_in[5];
    const float* b_v    = (const float*)d_in[6];
    const float* w_pe   = (const float*)d_in[7];
    const float* s_pe   = (const float*)d_in[8];
    const float* b_pe   = (const float*)d_in[9];
    const float* w_proj = (const float*)d_in[10];
    const float* s_proj = (const float*)d_in[11];
    const float* b_proj = (const float*)d_in[12];
    float* out = (float*)d_out;

    char* p = (char*)d_ws;
    us* qtb     = (us*)p;                  p += (size_t)8 * 4096 * 512 * 2;   // 32M
    us* vbuf    = (us*)p;                  p += (size_t)8 * 256 * 4096 * 2;   // 16M
    us* opp     = (us*)p;                  p += (size_t)8 * 256 * 4096 * 2;   // 16M
    us* wqkh    = (us*)p;                  p += (size_t)512 * 256 * 2;
    us* wvh     = (us*)p;                  p += (size_t)256 * 256 * 2;
    us* wprojh  = (us*)p;                  p += (size_t)256 * 256 * 2;
    float* bqkp = (float*)p;

    prep_kernel<<<1024, 256, 0, stream>>>(w_qk, s_qk, b_qk, w_v, s_v,
                                          w_proj, s_proj, wqkh, wvh, wprojh, bqkp);
    qkv_kernel<<<dim3(64, 8), 256, 0, stream>>>(x, wqkh, bqkp, wvh, b_v, qtb, vbuf);
    pe_conv_kernel<<<dim3(256, 8), 256, 0, stream>>>(vbuf, w_pe, s_pe, b_pe, opp);
    attn_kernel<<<dim3(8, 8, 32), 256, 0, stream>>>(qtb, vbuf, opp);
    proj_kernel<<<dim3(64, 8), 256, 0, stream>>>(opp, wprojh, b_proj, out);
}

// Round 17
// 151.187 us; speedup vs baseline: 1.1726x; 1.0087x over previous
//
#include <hip/hip_runtime.h>
#include <math.h>

// AAttn bf16-MFMA pipeline v11. B=8, C=256, H=W=64, N=4096, AREA=4.
// ws: qt   bf16 [8][4096][512]  (q ch0..255 scaled by d^-.5*log2e, k ch256..511)
//     vbuf bf16 [8][256][4096]
//     opp  bf16 [8][256][4096]  (pp then += attention out)
//     wqkh/wvh/wprojh bf16 weights in MFMA-FRAGMENT order
// v11 = v10 with pe_conv rewritten: register-window conv (8 px/task from
//       4x float4 row loads) kills the 25-scalar-LDS-reads-per-pixel issue
//       bottleneck; us8 vector stores; cvt_pk converts.

#define NN 4096
#define NA 1024

typedef unsigned short us;
typedef __attribute__((ext_vector_type(4))) unsigned short us4;
typedef __attribute__((ext_vector_type(8))) unsigned short us8;
typedef __attribute__((ext_vector_type(8))) short bf16x8;
typedef __attribute__((ext_vector_type(4))) float f32x4;

#define QS (0.17677669529663687f * 1.4426950408889634f)   // d^-0.5 * log2(e)

__device__ __forceinline__ us f2b(float f) {
    unsigned u = __builtin_bit_cast(unsigned, f);
    u += 0x7fffu + ((u >> 16) & 1u);              // RNE
    return (us)(u >> 16);
}
__device__ __forceinline__ float b2f(us h) {
    unsigned u = ((unsigned)h) << 16;
    return __builtin_bit_cast(float, u);
}
__device__ __forceinline__ unsigned pack2(float lo, float hi) {
    return (unsigned)f2b(lo) | ((unsigned)f2b(hi) << 16);
}
__device__ __forceinline__ unsigned cvtpk_bf16(float lo, float hi) {
    unsigned r;
    asm("v_cvt_pk_bf16_f32 %0, %1, %2" : "=v"(r) : "v"(lo), "v"(hi));
    return r;
}
// raw 2^x: inputs bounded here so libm's denormal fixup is dead weight
__device__ __forceinline__ float fexp2(float x) {
    float r;
    asm("v_exp_f32 %0, %1" : "=v"(r) : "v"(x));
    return r;
}

// fragment-order index: (ch,k) -> ((ch>>4)*8 + (k>>5))*512 + (((k>>3)&3)*16 + (ch&15))*8 + (k&7)
__device__ __forceinline__ size_t wswz(int ch, int k) {
    return ((size_t)((ch >> 4) * 8 + (k >> 5))) * 512 + ((((k >> 3) & 3) * 16 + (ch & 15))) * 8 + (k & 7);
}

// ---------------- weight prep: fold BN scale, bf16, fragment order ----------
__global__ __launch_bounds__(256) void prep_kernel(
    const float* __restrict__ w_qk, const float* __restrict__ s_qk, const float* __restrict__ b_qk,
    const float* __restrict__ w_v,  const float* __restrict__ s_v,
    const float* __restrict__ w_proj, const float* __restrict__ s_proj,
    us* __restrict__ wqkh, us* __restrict__ wvh, us* __restrict__ wprojh,
    float* __restrict__ bqkp)
{
    int idx = blockIdx.x * 256 + threadIdx.x;
    if (idx < 131072) {
        int o = idx >> 8, k = idx & 255;
        float sc = s_qk[o] * (o < 256 ? QS : 1.0f);
        wqkh[wswz(o, k)] = f2b(w_qk[idx] * sc);
    } else if (idx < 196608) {
        int j = idx - 131072; int o = j >> 8, k = j & 255;
        wvh[wswz(o, k)] = f2b(w_v[j] * s_v[o]);
    } else {
        int j = idx - 196608; int o = j >> 8, k = j & 255;
        wprojh[wswz(o, k)] = f2b(w_proj[j] * s_proj[o]);
    }
    if (idx < 512) bqkp[idx] = b_qk[idx] * (idx < 256 ? QS : 1.0f);
}

// ---------------- qkv GEMM: x f32 staged once (64-pos strips), 12 ch-groups -
__global__ __launch_bounds__(256) void qkv_kernel(
    const float* __restrict__ x,
    const us* __restrict__ wqkh, const float* __restrict__ bqkp,
    const us* __restrict__ wvh,  const float* __restrict__ b_v,
    us* __restrict__ qt, us* __restrict__ vbuf)
{
    const int n0 = blockIdx.x * 64;
    const int b  = blockIdx.y;
    const int tid = threadIdx.x;
    const int w = tid >> 6, lane = tid & 63, c = lane & 15, g = lane >> 4;

    __shared__ __align__(16) us Xs[64][264];   // [pos][cin], 528B rows

    const float* Xb = x + (size_t)b * 256 * NN;
    #pragma unroll
    for (int i = 0; i < 16; i++) {
        int t = tid + i * 256;                 // 4096 tasks: 128 cin-pairs x 32 pos-pairs
        int cp = t >> 5, pp = t & 31;
        const float* r0 = Xb + (size_t)(2 * cp) * NN + n0 + 2 * pp;
        float2 a0 = *(const float2*)r0;
        float2 a1 = *(const float2*)(r0 + NN);
        *(unsigned*)&Xs[2 * pp][2 * cp]     = pack2(a0.x, a1.x);
        *(unsigned*)&Xs[2 * pp + 1][2 * cp] = pack2(a0.y, a1.y);
    }
    __syncthreads();

    for (int grp = 0; grp < 3; grp++) {
        f32x4 acc[4][4] = {};                  // [cgi][j]
        for (int kc = 0; kc < 256; kc += 32) {
            bf16x8 Xf[4];
            #pragma unroll
            for (int j = 0; j < 4; j++)
                Xf[j] = *(const bf16x8*)&Xs[j * 16 + c][kc + g * 8];
            #pragma unroll
            for (int cgi = 0; cgi < 4; cgi++) {
                int chbase = (grp < 2 ? (grp * 4 + cgi) * 64 : cgi * 64);
                const us* Wp = (grp < 2 ? wqkh : wvh) +
                    ((size_t)(((chbase >> 4) + w) * 8 + (kc >> 5))) * 512 + lane * 8;
                bf16x8 Wf = *(const bf16x8*)Wp;   // coalesced 1KB wave load
                if (grp < 2) {   // A=X(pos), B=W(ch) -> D[pos][ch]
                    #pragma unroll
                    for (int j = 0; j < 4; j++)
                        acc[cgi][j] = __builtin_amdgcn_mfma_f32_16x16x32_bf16(Xf[j], Wf, acc[cgi][j], 0, 0, 0);
                } else {         // A=W(ch), B=X(pos) -> D[ch][pos]
                    #pragma unroll
                    for (int j = 0; j < 4; j++)
                        acc[cgi][j] = __builtin_amdgcn_mfma_f32_16x16x32_bf16(Wf, Xf[j], acc[cgi][j], 0, 0, 0);
                }
            }
        }
        if (grp < 2) {
            #pragma unroll
            for (int cgi = 0; cgi < 4; cgi++) {
                int ch = (grp * 4 + cgi) * 64 + w * 16 + c;
                float bb = bqkp[ch];
                #pragma unroll
                for (int j = 0; j < 4; j++)
                    #pragma unroll
                    for (int r = 0; r < 4; r++)
                        qt[((size_t)b * 4096 + n0 + j * 16 + g * 4 + r) * 512 + ch] =
                            f2b(acc[cgi][j][r] + bb);
            }
        } else {
            #pragma unroll
            for (int cgi = 0; cgi < 4; cgi++)
                #pragma unroll
                for (int r = 0; r < 4; r++) {
                    int ch = cgi * 64 + w * 16 + g * 4 + r;
                    float bb = b_v[ch];
                    #pragma unroll
                    for (int j = 0; j < 4; j++)
                        vbuf[((size_t)b * 256 + ch) * NN + n0 + j * 16 + c] =
                            f2b(acc[cgi][j][r] + bb);
                }
        }
    }
}

// ---------------- depthwise 5x5 'SAME': register-window conv ----------------
// each thread: 2 tasks of 8 consecutive px in one row; per tap-row 4x float4
// loads cover cols c0-4..c0+11 (edges zeroed); all 25 taps from registers.
__global__ __launch_bounds__(256) void pe_conv_kernel(
    const us* __restrict__ vbuf,
    const float* __restrict__ w_pe, const float* __restrict__ s_pe, const float* __restrict__ b_pe,
    us* __restrict__ opp)
{
    const int c = blockIdx.x, b = blockIdx.y;
    const int tid = threadIdx.x;
    const us* vp = vbuf + ((size_t)b * 256 + c) * NN;
    __shared__ __align__(16) float plane[4096];
    __shared__ float wloc[25];
    #pragma unroll
    for (int i = 0; i < 4; i++) {
        int idx = tid + i * 256;
        us4 v = *(const us4*)&vp[idx * 4];
        float4 f;
        f.x = b2f(v[0]); f.y = b2f(v[1]); f.z = b2f(v[2]); f.w = b2f(v[3]);
        *(float4*)&plane[idx * 4] = f;
    }
    if (tid < 25) wloc[tid] = w_pe[c * 25 + tid];
    __syncthreads();

    const float s = s_pe[c], bb = b_pe[c];
    us* op = opp + ((size_t)b * 256 + c) * NN;
    const int r0 = tid >> 3;           // 0..31
    const int c0 = (tid & 7) * 8;      // 0,8,...,56

    #pragma unroll
    for (int i = 0; i < 2; i++) {
        const int r = r0 + i * 32;
        float acc[8] = {};
        #pragma unroll
        for (int dy = -2; dy <= 2; dy++) {
            int hy = r + dy;
            if (hy < 0 || hy > 63) continue;
            const float* rp = &plane[hy * 64];
            float wnd[16];
            float4 A, B_, C_, D;
            if (c0 >= 4) A = *(const float4*)&rp[c0 - 4];
            else         A = float4{0.f, 0.f, 0.f, 0.f};
            B_ = *(const float4*)&rp[c0];
            C_ = *(const float4*)&rp[c0 + 4];
            if (c0 <= 52) D = *(const float4*)&rp[c0 + 8];
            else          D = float4{0.f, 0.f, 0.f, 0.f};
            wnd[0] = A.x;  wnd[1] = A.y;  wnd[2] = A.z;  wnd[3] = A.w;
            wnd[4] = B_.x; wnd[5] = B_.y; wnd[6] = B_.z; wnd[7] = B_.w;
            wnd[8] = C_.x; wnd[9] = C_.y; wnd[10] = C_.z; wnd[11] = C_.w;
            wnd[12] = D.x; wnd[13] = D.y; wnd[14] = D.z; wnd[15] = D.w;
            #pragma unroll
            for (int dx = -2; dx <= 2; dx++) {
                float wv = wloc[(dy + 2) * 5 + (dx + 2)];
                #pragma unroll
                for (int j = 0; j < 8; j++)
                    acc[j] = fmaf(wnd[4 + j + dx], wv, acc[j]);
            }
        }
        us8 o;
        #pragma unroll
        for (int j = 0; j < 4; j++) {
            unsigned pr = cvtpk_bf16(acc[2 * j] * s + bb, acc[2 * j + 1] * s + bb);
            o[2 * j]     = (us)(pr & 0xFFFFu);
            o[2 * j + 1] = (us)(pr >> 16);
        }
        *(us8*)&op[r * 64 + c0] = o;
    }
}

// ---------------- flash attention v8 core, bf16 opp epilogue ----------------
__global__ __launch_bounds__(256) void attn_kernel(
    const us* __restrict__ qt, const us* __restrict__ vbuf, us* __restrict__ opp)
{
    const int h   = blockIdx.x;   // 8  (x so same-(h,ba) blocks share XCD L2)
    const int qtb = blockIdx.y;   // 8 q-tiles of 128
    const int ba  = blockIdx.z;   // 32
    const int b = ba >> 2, a = ba & 3;
    const int tid = threadIdx.x;
    const int w = tid >> 6, lane = tid & 63, c = lane & 15, g = lane >> 4;
    const int q0 = qtb * 128;

    __shared__ __align__(16) us Kt[2][64][40];    // [key][d] dbuf
    __shared__ __align__(16) us Vs[2][2048];      // 32 rows x 128B, XOR-swizzled 16B slots
    __shared__ __align__(16) us Ps[128][72];      // wave-private rows

    // staging roles (one 16B load+write per buffer per thread)
    const int krow = tid >> 2, kseg = tid & 3;    // 64 rows x 32 d
    const int vrow = tid >> 3, vseg = tid & 7;    // 32 rows x 64 keys
    const int vbyte = vrow * 128 + ((vseg ^ (vrow & 7)) << 4);

    const us* Kg = qt + ((size_t)b * 4096 + a * NA) * 512 + 256 + h * 32;
    const us* Vg = vbuf + ((size_t)b * 256 + h * 32) * NN + a * NA;

    // Q fragments direct to registers
    const us* Qp = qt + ((size_t)b * 4096 + a * NA + q0 + w * 16 + c) * 512 + h * 32 + g * 8;
    const bf16x8 Qf0 = *(const bf16x8*)Qp;
    const bf16x8 Qf1 = *(const bf16x8*)(Qp + (size_t)64 * 512);

    // prologue: stage tile 0
    {
        us8 kreg = *(const us8*)(Kg + (size_t)krow * 512 + kseg * 8);
        us8 vreg = *(const us8*)(Vg + (size_t)vrow * NN + vseg * 8);
        *(us8*)&Kt[0][krow][kseg * 8] = kreg;
        *(us8*)((char*)Vs[0] + vbyte) = vreg;
    }
    __syncthreads();

    const bf16x8 ones = {0x3F80, 0x3F80, 0x3F80, 0x3F80, 0x3F80, 0x3F80, 0x3F80, 0x3F80};
    const f32x4 z = {0.f, 0.f, 0.f, 0.f};
    const int qr0 = w * 16 + c, qr1 = 64 + w * 16 + c;

    f32x4 O0a = z, O1a = z, Osa = z;
    f32x4 O0b = z, O1b = z, Osb = z;
    int cur = 0;

    for (int kt = 0; kt < 16; kt++) {
        // issue next tile's global loads early (latency hides under compute)
        us8 kreg, vreg;
        if (kt < 15) {
            const int kv1 = (kt + 1) * 64;
            kreg = *(const us8*)(Kg + ((size_t)(kv1 + krow)) * 512 + kseg * 8);
            vreg = *(const us8*)(Vg + (size_t)vrow * NN + kv1 + vseg * 8);
        }

        // S^T: A=K rows, B=Q halves -> S[key=j*16+g*4+r][q]
        f32x4 sA[4], sB[4];
        #pragma unroll
        for (int j = 0; j < 4; j++) {
            bf16x8 Kf = *(const bf16x8*)&Kt[cur][j * 16 + c][g * 8];
            sA[j] = __builtin_amdgcn_mfma_f32_16x16x32_bf16(Kf, Qf0, z, 0, 0, 0);
            sB[j] = __builtin_amdgcn_mfma_f32_16x16x32_bf16(Kf, Qf1, z, 0, 0, 0);
        }

        // half a: exp2 + pack -> Ps rows 0..63
        #pragma unroll
        for (int j = 0; j < 4; j++) {
            uint2 pr;
            pr.x = cvtpk_bf16(fexp2(sA[j][0]), fexp2(sA[j][1]));
            pr.y = cvtpk_bf16(fexp2(sA[j][2]), fexp2(sA[j][3]));
            *(uint2*)&Ps[qr0][j * 16 + g * 4] = pr;
        }
        asm volatile("s_waitcnt lgkmcnt(0)" ::: "memory");
        __builtin_amdgcn_sched_barrier(0);

        // half b exp2/pack (trans+VALU) overlaps PV-a MFMAs below
        uint2 prb[4];
        #pragma unroll
        for (int j = 0; j < 4; j++) {
            prb[j].x = cvtpk_bf16(fexp2(sB[j][0]), fexp2(sB[j][1]));
            prb[j].y = cvtpk_bf16(fexp2(sB[j][2]), fexp2(sB[j][3]));
        }

        // PV-a: O += P V ; l += P * 1
        #pragma unroll
        for (int ks = 0; ks < 2; ks++) {
            int so = (((ks * 4 + g) ^ (c & 7)) << 4);
            bf16x8 Bv0 = *(const bf16x8*)((char*)Vs[cur] + c * 128 + so);
            bf16x8 Bv1 = *(const bf16x8*)((char*)Vs[cur] + (16 + c) * 128 + so);
            bf16x8 Ap0 = *(const bf16x8*)&Ps[qr0][ks * 32 + g * 8];
            O0a = __builtin_amdgcn_mfma_f32_16x16x32_bf16(Ap0, Bv0, O0a, 0, 0, 0);
            O1a = __builtin_amdgcn_mfma_f32_16x16x32_bf16(Ap0, Bv1, O1a, 0, 0, 0);
            Osa = __builtin_amdgcn_mfma_f32_16x16x32_bf16(Ap0, ones, Osa, 0, 0, 0);
        }

        // half b: write packs -> Ps rows 64..127
        #pragma unroll
        for (int j = 0; j < 4; j++)
            *(uint2*)&Ps[qr1][j * 16 + g * 4] = prb[j];
        asm volatile("s_waitcnt lgkmcnt(0)" ::: "memory");
        __builtin_amdgcn_sched_barrier(0);

        // PV-b
        #pragma unroll
        for (int ks = 0; ks < 2; ks++) {
            int so = (((ks * 4 + g) ^ (c & 7)) << 4);
            bf16x8 Bv0 = *(const bf16x8*)((char*)Vs[cur] + c * 128 + so);
            bf16x8 Bv1 = *(const bf16x8*)((char*)Vs[cur] + (16 + c) * 128 + so);
            bf16x8 Ap1 = *(const bf16x8*)&Ps[qr1][ks * 32 + g * 8];
            O0b = __builtin_amdgcn_mfma_f32_16x16x32_bf16(Ap1, Bv0, O0b, 0, 0, 0);
            O1b = __builtin_amdgcn_mfma_f32_16x16x32_bf16(Ap1, Bv1, O1b, 0, 0, 0);
            Osb = __builtin_amdgcn_mfma_f32_16x16x32_bf16(Ap1, ones, Osb, 0, 0, 0);
        }

        // write next buffer (compiler inserts vmcnt wait for kreg/vreg)
        if (kt < 15) {
            *(us8*)&Kt[cur ^ 1][krow][kseg * 8] = kreg;
            *(us8*)((char*)Vs[cur ^ 1] + vbyte) = vreg;
        }
        __syncthreads();
        cur ^= 1;
    }

    // Osum[r] = l for q-row (PV layout); RMW bf16 opp, both q-halves
    float linva[4], linvb[4];
    #pragma unroll
    for (int r = 0; r < 4; r++) { linva[r] = 1.0f / Osa[r]; linvb[r] = 1.0f / Osb[r]; }

    us* Ob = opp + ((size_t)(b * 256 + h * 32)) * NN + a * NA + q0 + w * 16 + g * 4;
    {
        us4 o = *(us4*)(Ob + (size_t)c * NN);
        #pragma unroll
        for (int r = 0; r < 4; r++) o[r] = f2b(b2f(o[r]) + O0a[r] * linva[r]);
        *(us4*)(Ob + (size_t)c * NN) = o;
        us4 o2 = *(us4*)(Ob + (size_t)(16 + c) * NN);
        #pragma unroll
        for (int r = 0; r < 4; r++) o2[r] = f2b(b2f(o2[r]) + O1a[r] * linva[r]);
        *(us4*)(Ob + (size_t)(16 + c) * NN) = o2;

        us* Ob2 = Ob + 64;
        us4 o3 = *(us4*)(Ob2 + (size_t)c * NN);
        #pragma unroll
        for (int r = 0; r < 4; r++) o3[r] = f2b(b2f(o3[r]) + O0b[r] * linvb[r]);
        *(us4*)(Ob2 + (size_t)c * NN) = o3;
        us4 o4 = *(us4*)(Ob2 + (size_t)(16 + c) * NN);
        #pragma unroll
        for (int r = 0; r < 4; r++) o4[r] = f2b(b2f(o4[r]) + O1b[r] * linvb[r]);
        *(us4*)(Ob2 + (size_t)(16 + c) * NN) = o4;
    }
}

// ---------------- proj GEMM: bf16 opp staged once, 4 ch-groups --------------
__global__ __launch_bounds__(256) void proj_kernel(
    const us* __restrict__ opp,
    const us* __restrict__ wprojh, const float* __restrict__ b_proj,
    float* __restrict__ out)
{
    const int n0 = blockIdx.x * 64;
    const int b  = blockIdx.y;
    const int tid = threadIdx.x;
    const int w = tid >> 6, lane = tid & 63, c = lane & 15, g = lane >> 4;

    __shared__ __align__(16) us Xs[64][264];

    const us* Xb = opp + (size_t)b * 256 * NN;
    #pragma unroll
    for (int i = 0; i < 16; i++) {
        int t = tid + i * 256;
        int cp = t >> 5, pp = t & 31;
        unsigned a0 = *(const unsigned*)&Xb[(size_t)(2 * cp) * NN + n0 + 2 * pp];
        unsigned a1 = *(const unsigned*)&Xb[(size_t)(2 * cp + 1) * NN + n0 + 2 * pp];
        *(unsigned*)&Xs[2 * pp][2 * cp]     = (a0 & 0xFFFFu) | (a1 << 16);
        *(unsigned*)&Xs[2 * pp + 1][2 * cp] = (a0 >> 16) | (a1 & 0xFFFF0000u);
    }
    __syncthreads();

    f32x4 acc[4][4] = {};                      // [cgi][j]
    for (int kc = 0; kc < 256; kc += 32) {
        bf16x8 Xf[4];
        #pragma unroll
        for (int j = 0; j < 4; j++)
            Xf[j] = *(const bf16x8*)&Xs[j * 16 + c][kc + g * 8];
        #pragma unroll
        for (int cgi = 0; cgi < 4; cgi++) {
            const us* Wp = wprojh +
                ((size_t)((cgi * 4 + w) * 8 + (kc >> 5))) * 512 + lane * 8;
            bf16x8 Wf = *(const bf16x8*)Wp;    // coalesced 1KB wave load
            #pragma unroll
            for (int j = 0; j < 4; j++)    // A=W(ch), B=X(pos) -> D[ch][pos]
                acc[cgi][j] = __builtin_amdgcn_mfma_f32_16x16x32_bf16(Wf, Xf[j], acc[cgi][j], 0, 0, 0);
        }
    }

    #pragma unroll
    for (int cgi = 0; cgi < 4; cgi++)
        #pragma unroll
        for (int r = 0; r < 4; r++) {
            int ch = cgi * 64 + w * 16 + g * 4 + r;
            float bb = b_proj[ch];
            #pragma unroll
            for (int j = 0; j < 4; j++)
                out[((size_t)b * 256 + ch) * NN + n0 + j * 16 + c] = acc[cgi][j][r] + bb;
        }
}

extern "C" void kernel_launch(void* const* d_in, const int* in_sizes, int n_in,
                              void* d_out, int out_size, void* d_ws, size_t ws_size,
                              hipStream_t stream) {
    const float* x      = (const float*)d_in[0];
    const float* w_qk   = (const float*)d_in[1];
    const float* s_qk   = (const float*)d_in[2];
    const float* b_qk   = (const float*)d_in[3];
    const float* w_v    = (const float*)d_in[4];
    const float* s_v    = (const float*)d_in[5];
    const float* b_v    = (const float*)d_in[6];
    const float* w_pe   = (const float*)d_in[7];
    const float* s_pe   = (const float*)d_in[8];
    const float* b_pe   = (const float*)d_in[9];
    const float* w_proj = (const float*)d_in[10];
    const float* s_proj = (const float*)d_in[11];
    const float* b_proj = (const float*)d_in[12];
    float* out = (float*)d_out;

    char* p = (char*)d_ws;
    us* qtb     = (us*)p;                  p += (size_t)8 * 4096 * 512 * 2;   // 32M
    us* vbuf    = (us*)p;                  p += (size_t)8 * 256 * 4096 * 2;   // 16M
    us* opp     = (us*)p;                  p += (size_t)8 * 256 * 4096 * 2;   // 16M
    us* wqkh    = (us*)p;                  p += (size_t)512 * 256 * 2;
    us* wvh     = (us*)p;                  p += (size_t)256 * 256 * 2;
    us* wprojh  = (us*)p;                  p += (size_t)256 * 256 * 2;
    float* bqkp = (float*)p;

    prep_kernel<<<1024, 256, 0, stream>>>(w_qk, s_qk, b_qk, w_v, s_v,
                                          w_proj, s_proj, wqkh, wvh, wprojh, bqkp);
    qkv_kernel<<<dim3(64, 8), 256, 0, stream>>>(x, wqkh, bqkp, wvh, b_v, qtb, vbuf);
    pe_conv_kernel<<<dim3(256, 8), 256, 0, stream>>>(vbuf, w_pe, s_pe, b_pe, opp);
    attn_kernel<<<dim3(8, 8, 32), 256, 0, stream>>>(qtb, vbuf, opp);
    proj_kernel<<<dim3(64, 8), 256, 0, stream>>>(opp, wprojh, b_proj, out);
}